// Round 1
// baseline (200.232 us; speedup 1.0000x reference)
//
#include <hip/hip_runtime.h>
#include <stdint.h>

#define N    4096
#define EMB  256
#define NH   4
#define HC   64     // channels per head
#define PAD  40     // LDS inner stride (elements): 80B = 20 banks -> <=2-way
#define KSPLIT 8
#define BJ   32

typedef __attribute__((ext_vector_type(8))) short s16x8;   // 8 bf16 frag
typedef __attribute__((ext_vector_type(4))) float f32x4;
typedef __attribute__((ext_vector_type(4))) int   i32x4;
typedef unsigned short ushort_t;

__device__ __forceinline__ unsigned short f2bf(float f) {
  unsigned int u = __builtin_bit_cast(unsigned int, f);
  u += 0x7fffu + ((u >> 16) & 1u);      // RNE (finite values only)
  return (unsigned short)(u >> 16);
}
__device__ __forceinline__ float bf2f(unsigned short b) {
  unsigned int u = ((unsigned int)b) << 16;
  return __builtin_bit_cast(float, u);
}

// ---------------- K0: W[k][m] -> WT[m][k] as bf16 ----------------
__global__ void k_transpose_bf(const float* __restrict__ W, ushort_t* __restrict__ WT) {
  int m = blockIdx.x;
  int k = threadIdx.x;
  WT[m * EMB + k] = f2bf(W[k * EMB + m]);
}

// ---------------- K1: h = x @ W_lin (bf16 MFMA), epilogue:
//   hT[h][c][node] (bf16), a_src[node][h], a_dst[node][h] (fp32 from acc) ----
__global__ __launch_bounds__(256)
void k1_gemm_h(const float* __restrict__ x,
               const ushort_t* __restrict__ WlT,      // [256 m][256 k]
               const float* __restrict__ att_src,     // [4][64]
               const float* __restrict__ att_dst,
               ushort_t* __restrict__ hT,             // [4][64][4096]
               float* __restrict__ a_src,             // [4096][4]
               float* __restrict__ a_dst)
{
  __shared__ ushort_t A_lds[64][PAD];
  __shared__ ushort_t B_lds[64][PAD];
  const int t = threadIdx.x;
  const int lane = t & 63;
  const int w = t >> 6;
  const int i0 = blockIdx.x * 64;
  const int head = blockIdx.y;
  const int c0 = head * 64;
  const int lq = lane >> 4, lm = lane & 15;
  const int srow = t >> 2, sko = (t & 3) * 8;

  f32x4 acc[4];
  #pragma unroll
  for (int nf = 0; nf < 4; ++nf) acc[nf] = f32x4{0.f, 0.f, 0.f, 0.f};

  for (int k0 = 0; k0 < EMB; k0 += 32) {
    __syncthreads();
    {
      const float* src = x + (i0 + srow) * EMB + k0 + sko;
      f32x4 v0 = *(const f32x4*)src;
      f32x4 v1 = *(const f32x4*)(src + 4);
      s16x8 p;
      p[0]=(short)f2bf(v0[0]); p[1]=(short)f2bf(v0[1]); p[2]=(short)f2bf(v0[2]); p[3]=(short)f2bf(v0[3]);
      p[4]=(short)f2bf(v1[0]); p[5]=(short)f2bf(v1[1]); p[6]=(short)f2bf(v1[2]); p[7]=(short)f2bf(v1[3]);
      *(s16x8*)&A_lds[srow][sko] = p;
      *(s16x8*)&B_lds[srow][sko] = *(const s16x8*)(WlT + (c0 + srow) * EMB + k0 + sko);
    }
    __syncthreads();
    s16x8 a = *(const s16x8*)&A_lds[w * 16 + lm][lq * 8];
    #pragma unroll
    for (int nf = 0; nf < 4; ++nf) {
      s16x8 b = *(const s16x8*)&B_lds[nf * 16 + lm][lq * 8];
      acc[nf] = __builtin_amdgcn_mfma_f32_16x16x32_bf16(a, b, acc[nf], 0, 0, 0);
    }
  }

  float ps[4] = {0.f,0.f,0.f,0.f}, pd[4] = {0.f,0.f,0.f,0.f};
  #pragma unroll
  for (int nf = 0; nf < 4; ++nf) {
    float wsv = att_src[c0 + nf * 16 + lm];
    float wdv = att_dst[c0 + nf * 16 + lm];
    #pragma unroll
    for (int r = 0; r < 4; ++r) {
      float v = acc[nf][r];
      int node = w * 16 + lq * 4 + r;                 // D: row=(lane>>4)*4+reg, col=lane&15
      hT[(c0 + nf * 16 + lm) * N + i0 + node] = f2bf(v);
      ps[r] += v * wsv;
      pd[r] += v * wdv;
    }
  }
  #pragma unroll
  for (int r = 0; r < 4; ++r) {
    #pragma unroll
    for (int mm = 1; mm < 16; mm <<= 1) {
      ps[r] += __shfl_xor(ps[r], mm);
      pd[r] += __shfl_xor(pd[r], mm);
    }
  }
  if (lm == 0) {
    #pragma unroll
    for (int r = 0; r < 4; ++r) {
      int node = i0 + w * 16 + lq * 4 + r;
      a_src[node * NH + head] = ps[r];
      a_dst[node * NH + head] = pd[r];
    }
  }
}

// ---------------- K34: fused masked-softmax numerator/denominator ----------
// block: 64 dest rows x 256 cols (wave w = head w, 64x64). grid (N/64, KSPLIT).
// Single pass: acc += e * h  (bf16 MFMA), l += e  (fp32). No max-sub (scores
// bounded ~|6|, exp safe). Split-K partials via fp32 atomics.
__global__ __launch_bounds__(256, 2)
void k34_attn(const int* __restrict__ adj,
              const ushort_t* __restrict__ hT,       // [4][64][4096]
              const float* __restrict__ a_src,       // [4096][4]
              const float* __restrict__ a_dst,
              float* __restrict__ acc_buf,           // [4096][256] (zeroed)
              float* __restrict__ l_buf)             // [4096][4]   (zeroed)
{
  __shared__ ushort_t A_lds[NH][64][PAD];   // e-tile per head [i][j]
  __shared__ ushort_t B_lds[NH][64][PAD];   // h-tile per head [c][j]
  __shared__ float as_lds[BJ][NH];
  __shared__ float l_red[64][4][NH];

  const int t = threadIdx.x;
  const int lane = t & 63;
  const int w = t >> 6;            // wave id == head (mfma) == j-quad (staging)
  const int i0 = blockIdx.x * 64;
  const int j0base = blockIdx.y * (N / KSPLIT);
  const int lq = lane >> 4, lm = lane & 15;
  const int il = lane;             // i-local / c-local in staging
  const int jq = w;

  f32x4 ad = *(const f32x4*)(a_dst + (i0 + il) * NH);

  f32x4 acc[4][4];
  #pragma unroll
  for (int a = 0; a < 4; ++a)
    #pragma unroll
    for (int b = 0; b < 4; ++b) acc[a][b] = f32x4{0.f, 0.f, 0.f, 0.f};

  float lp[NH] = {0.f, 0.f, 0.f, 0.f};

  for (int it = 0; it < (N / KSPLIT) / BJ; ++it) {
    const int j0 = j0base + it * BJ;
    __syncthreads();                                  // prev iter LDS reads done
    if (t < BJ) {
      *(f32x4*)&as_lds[t][0] = *(const f32x4*)(a_src + (j0 + t) * NH);
    }
    // issue global loads early (B tile regs + adj), consume after barrier
    s16x8 breg[4];
    {
      const ushort_t* src = hT + (w * HC + il) * N + j0;     // head=w, c=il
      #pragma unroll
      for (int u = 0; u < 4; ++u) breg[u] = *(const s16x8*)(src + u * 8);
    }
    i32x4 av0 = *(const i32x4*)(adj + (i0 + il) * N + j0 + jq * 8);
    i32x4 av1 = *(const i32x4*)(adj + (i0 + il) * N + j0 + jq * 8 + 4);
    __syncthreads();                                  // as_lds visible
    {
      int adjv[8];
      #pragma unroll
      for (int u = 0; u < 4; ++u) { adjv[u] = av0[u]; adjv[4 + u] = av1[u]; }
      unsigned short pk[NH][8];
      #pragma unroll
      for (int jj = 0; jj < 8; ++jj) {
        int jg = j0 + jq * 8 + jj;
        bool con = (adjv[jj] != 0) || (jg == i0 + il);        // self-loop
        f32x4 as = *(const f32x4*)&as_lds[jq * 8 + jj][0];
        #pragma unroll
        for (int h = 0; h < NH; ++h) {
          float s = as[h] + ad[h];
          s = (s >= 0.f) ? s : 0.2f * s;                      // leaky relu
          float e = con ? __expf(s) : 0.f;
          unsigned short eb = f2bf(e);
          pk[h][jj] = eb;
          lp[h] += bf2f(eb);      // denominator sums the SAME rounded value
        }
      }
      #pragma unroll
      for (int h = 0; h < NH; ++h) {
        s16x8 p;
        #pragma unroll
        for (int jj = 0; jj < 8; ++jj) p[jj] = (short)pk[h][jj];
        *(s16x8*)&A_lds[h][il][jq * 8] = p;
      }
      #pragma unroll
      for (int u = 0; u < 4; ++u) *(s16x8*)&B_lds[w][il][u * 8] = breg[u];
    }
    __syncthreads();                                  // staging visible
    s16x8 af[4], bfr[4];
    #pragma unroll
    for (int mf = 0; mf < 4; ++mf) af[mf] = *(const s16x8*)&A_lds[w][mf * 16 + lm][lq * 8];
    #pragma unroll
    for (int nf = 0; nf < 4; ++nf) bfr[nf] = *(const s16x8*)&B_lds[w][nf * 16 + lm][lq * 8];
    #pragma unroll
    for (int mf = 0; mf < 4; ++mf)
      #pragma unroll
      for (int nf = 0; nf < 4; ++nf)
        acc[mf][nf] = __builtin_amdgcn_mfma_f32_16x16x32_bf16(af[mf], bfr[nf], acc[mf][nf], 0, 0, 0);
  }

  // denominator reduction: partials are per (i=il, jq, h)
  #pragma unroll
  for (int h = 0; h < NH; ++h) l_red[il][jq][h] = lp[h];
  __syncthreads();
  {
    int i = t >> 2, h = t & 3;
    float s = l_red[i][0][h] + l_red[i][1][h] + l_red[i][2][h] + l_red[i][3][h];
    atomicAdd(&l_buf[(i0 + i) * NH + h], s);
  }
  // numerator partials
  #pragma unroll
  for (int mf = 0; mf < 4; ++mf)
    #pragma unroll
    for (int nf = 0; nf < 4; ++nf)
      #pragma unroll
      for (int r = 0; r < 4; ++r) {
        int node = i0 + mf * 16 + lq * 4 + r;
        int col = w * 64 + nf * 16 + lm;
        atomicAdd(&acc_buf[node * EMB + col], acc[mf][nf][r]);
      }
}

// ---------------- K4b: normalize + GAT bias, round to bf16 ----------------
__global__ void k4b_norm(const float* __restrict__ acc_buf,
                         const float* __restrict__ l_buf,
                         const float* __restrict__ bias_att,
                         ushort_t* __restrict__ oat)
{
  int idx = blockIdx.x * 256 + threadIdx.x;
  int node = idx >> 8;
  int hc = idx & 255;
  float v = acc_buf[idx] / l_buf[node * NH + (hc >> 6)] + bias_att[hc];
  oat[idx] = f2bf(v);
}

// ---------------- K5: y = oat @ W_out + b_out, then LayerNorm -------------
__global__ __launch_bounds__(256)
void k5_gemm_ln(const ushort_t* __restrict__ oat,    // [4096][256]
                const ushort_t* __restrict__ WoT,    // [256 m][256 k]
                const float* __restrict__ b_out,
                const float* __restrict__ gamma,
                const float* __restrict__ beta,
                float* __restrict__ out)
{
  __shared__ ushort_t A_lds[32][PAD];
  __shared__ ushort_t B_lds[256][PAD];
  __shared__ float y_lds[32][260];
  const int t = threadIdx.x, lane = t & 63, w = t >> 6;
  const int i0 = blockIdx.x * 32;
  const int lq = lane >> 4, lm = lane & 15;

  f32x4 acc[2][4];
  #pragma unroll
  for (int a = 0; a < 2; ++a)
    #pragma unroll
    for (int b = 0; b < 4; ++b) acc[a][b] = f32x4{0.f, 0.f, 0.f, 0.f};

  for (int k0 = 0; k0 < EMB; k0 += 32) {
    __syncthreads();
    if (t < 128) {
      int row = t >> 2, ko = (t & 3) * 8;
      *(s16x8*)&A_lds[row][ko] = *(const s16x8*)(oat + (i0 + row) * EMB + k0 + ko);
    }
    {
      const ushort_t* src = WoT + t * EMB + k0;
      #pragma unroll
      for (int u = 0; u < 4; ++u) *(s16x8*)&B_lds[t][u * 8] = *(const s16x8*)(src + u * 8);
    }
    __syncthreads();
    s16x8 a0 = *(const s16x8*)&A_lds[lm][lq * 8];
    s16x8 a1 = *(const s16x8*)&A_lds[16 + lm][lq * 8];
    #pragma unroll
    for (int nf = 0; nf < 4; ++nf) {
      s16x8 b = *(const s16x8*)&B_lds[w * 64 + nf * 16 + lm][lq * 8];
      acc[0][nf] = __builtin_amdgcn_mfma_f32_16x16x32_bf16(a0, b, acc[0][nf], 0, 0, 0);
      acc[1][nf] = __builtin_amdgcn_mfma_f32_16x16x32_bf16(a1, b, acc[1][nf], 0, 0, 0);
    }
  }
  #pragma unroll
  for (int mf = 0; mf < 2; ++mf)
    #pragma unroll
    for (int nf = 0; nf < 4; ++nf)
      #pragma unroll
      for (int r = 0; r < 4; ++r) {
        int row = mf * 16 + lq * 4 + r;
        int col = w * 64 + nf * 16 + lm;
        y_lds[row][col] = acc[mf][nf][r] + b_out[col];
      }
  __syncthreads();
  f32x4 g  = *(const f32x4*)(gamma + lane * 4);
  f32x4 be = *(const f32x4*)(beta + lane * 4);
  for (int r = w * 8; r < w * 8 + 8; ++r) {
    f32x4 v = *(const f32x4*)&y_lds[r][lane * 4];
    float s1 = v[0] + v[1] + v[2] + v[3];
    float s2 = v[0]*v[0] + v[1]*v[1] + v[2]*v[2] + v[3]*v[3];
    #pragma unroll
    for (int mm = 1; mm < 64; mm <<= 1) { s1 += __shfl_xor(s1, mm); s2 += __shfl_xor(s2, mm); }
    float mu = s1 * (1.f / 256.f);
    float var = s2 * (1.f / 256.f) - mu * mu;
    float rs = rsqrtf(var + 1e-5f);
    f32x4 o;
    #pragma unroll
    for (int u = 0; u < 4; ++u) o[u] = (v[u] - mu) * rs * g[u] + be[u];
    *(f32x4*)(out + (i0 + r) * EMB + lane * 4) = o;
  }
}

extern "C" void kernel_launch(void* const* d_in, const int* in_sizes, int n_in,
                              void* d_out, int out_size, void* d_ws, size_t ws_size,
                              hipStream_t stream)
{
  (void)in_sizes; (void)n_in; (void)out_size; (void)ws_size;
  const float* x        = (const float*)d_in[0];
  const int*   adj      = (const int*)d_in[1];
  const float* W_lin    = (const float*)d_in[2];
  const float* att_src  = (const float*)d_in[3];
  const float* att_dst  = (const float*)d_in[4];
  const float* bias_att = (const float*)d_in[5];
  const float* W_out    = (const float*)d_in[6];
  const float* b_out    = (const float*)d_in[7];
  const float* gamma    = (const float*)d_in[8];
  const float* beta     = (const float*)d_in[9];
  float* out = (float*)d_out;

  uint8_t* p = (uint8_t*)d_ws;
  ushort_t* WlT = (ushort_t*)p;  p += (size_t)EMB * EMB * sizeof(ushort_t);
  ushort_t* WoT = (ushort_t*)p;  p += (size_t)EMB * EMB * sizeof(ushort_t);
  ushort_t* hT  = (ushort_t*)p;  p += (size_t)NH * HC * N * sizeof(ushort_t);
  float* a_srcb = (float*)p;     p += (size_t)N * NH * sizeof(float);
  float* a_dstb = (float*)p;     p += (size_t)N * NH * sizeof(float);
  float* l_buf  = (float*)p;     p += (size_t)N * NH * sizeof(float);
  float* acc_buf= (float*)p;     p += (size_t)N * EMB * sizeof(float);
  ushort_t* oat = (ushort_t*)p;  p += (size_t)N * EMB * sizeof(ushort_t);

  k_transpose_bf<<<EMB, EMB, 0, stream>>>(W_lin, WlT);
  k_transpose_bf<<<EMB, EMB, 0, stream>>>(W_out, WoT);
  k1_gemm_h<<<dim3(N / 64, NH), 256, 0, stream>>>(x, WlT, att_src, att_dst, hT, a_srcb, a_dstb);
  hipMemsetAsync(acc_buf, 0, (size_t)N * EMB * sizeof(float), stream);
  hipMemsetAsync(l_buf, 0, (size_t)N * NH * sizeof(float), stream);
  k34_attn<<<dim3(N / 64, KSPLIT), 256, 0, stream>>>(adj, hT, a_srcb, a_dstb, acc_buf, l_buf);
  k4b_norm<<<(N * EMB) / 256, 256, 0, stream>>>(acc_buf, l_buf, bias_att, oat);
  k5_gemm_ln<<<N / 32, 256, 0, stream>>>(oat, WoT, b_out, gamma, beta, out);
}